// Round 11
// baseline (2579.923 us; speedup 1.0000x reference)
//
#include <hip/hip_runtime.h>
#include <stdint.h>

#define BATCH 16
#define NPTS 500000
#define QPTS (NPTS / 4)        // 125000 quads
#define DBITS 21
#define DSIZE (1u << DBITS)
#define VOFF 969696            // di = vid + VOFF in [0, 2^21)
#define HBINS 256
#define CAP 8192
#define KTOP 512
#define NBKT 64
#define CPB 32768              // cells per bucket
#define CAPL 16384             // uint16 list capacity per bucket (2.1x mean 7812)
#define MT 256                 // mega-kernel block threads
#define GRID 1024              // 256 CUs x 4 blocks/CU (LDS-limited) -> all co-resident
#define SCQ 512                // quads per scatter chunk (2048 points)
#define SCB ((QPTS + SCQ - 1) / SCQ)   // 245 chunks per batch
#define BCAP 128               // LDS per-bucket stack (mean 32, pow2)
#define CHQ ((QPTS + 255) / 256)       // 489 label chunks per batch
#define CCAP 262144            // compact entries capacity per batch (~100k used)
#define WBITS 11
#define WSIZE (1 << WBITS)
#define WMASK (WSIZE - 1)
#define WEMPTY 0xFFFFFFFFu
#define M_ORIGIN 0
// zero block: cursor(16*64) + ccur(16) + hist(16*256) + meta(16*8) + bar(8)
#define NZERO (BATCH * NBKT + BATCH + BATCH * HBINS + BATCH * 8 + 8)

typedef int ivec4 __attribute__((ext_vector_type(4)));
typedef unsigned short usvec8 __attribute__((ext_vector_type(8)));

// Must match JAX/np exactly: IEEE f32 divide (NOT *5.0f), trunc-toward-zero cast.
__device__ __forceinline__ uint32_t didx_of(float x, float y, float z) {
    int vx = (int)(x / 0.2f);
    int vy = (int)(y / 0.2f);
    int vz = (int)(z / 0.2f);
    int di = vx * 10000 + vy * 100 + vz + VOFF;
    di = di < 0 ? 0 : di;
    di = di > (int)DSIZE - 1 ? (int)DSIZE - 1 : di;  // unreachable (9.6 sigma); safety only
    return (uint32_t)di;
}

__device__ __forceinline__ void didx4_of(const float* base, int q, uint32_t di[4]) {
    const float4* cp = (const float4*)(base) + (size_t)q * 3;
    float4 f0 = cp[0], f1 = cp[1], f2 = cp[2];
    di[0] = didx_of(f0.x, f0.y, f0.z);
    di[1] = didx_of(f0.w, f1.x, f1.y);
    di[2] = didx_of(f1.z, f1.w, f2.x);
    di[3] = didx_of(f2.y, f2.z, f2.w);
}

__device__ __forceinline__ uint32_t bkt_of(uint32_t d) {
    return ((d >> 15) ^ (d >> 9)) & 63u;   // A ^ B: decorrelates Gaussian vx alignment
}

// Zeroes all control state (incl. grid-barrier counters) + fills winner hash.
__global__ void init_kernel(int* __restrict__ zero_base, unsigned int* __restrict__ winners) {
    int i = blockIdx.x * 256 + threadIdx.x;
    if (i < NZERO) zero_base[i] = 0;
    if (i < BATCH * WSIZE) winners[i] = WEMPTY;
}

// Device-scope arrive-and-wait barrier. Each barrier uses a FRESH counter (no reuse
// within a launch; init re-zeroes between launches). All GRID blocks are co-resident
// by construction (LDS 33.8KB -> max 4 blocks/CU; GRID = 256*4), so no deadlock.
__device__ __forceinline__ void grid_barrier(int* ctr) {
    __syncthreads();
    if (threadIdx.x == 0) {
        __threadfence();  // release: our plain stores visible device-wide
        __hip_atomic_fetch_add(ctr, 1, __ATOMIC_ACQ_REL, __HIP_MEMORY_SCOPE_AGENT);
        while (__hip_atomic_load(ctr, __ATOMIC_ACQUIRE, __HIP_MEMORY_SCOPE_AGENT) < GRID)
            __builtin_amdgcn_s_sleep(2);
        __threadfence();  // acquire: other blocks' stores visible to our block
    }
    __syncthreads();
}

// ONE kernel, 4 phases, 3 grid barriers. Saves ~13us fixed overhead per dropped dispatch.
__global__ void __launch_bounds__(MT, 4) mega_kernel(const float* __restrict__ coords,
                                                     uint16_t* __restrict__ lists,
                                                     int* __restrict__ cursor,
                                                     int* __restrict__ meta,
                                                     int* __restrict__ hist,
                                                     uint32_t* __restrict__ compact,
                                                     int* __restrict__ ccur,
                                                     unsigned int* __restrict__ winners,
                                                     int* __restrict__ bar,
                                                     int* __restrict__ out) {
    __shared__ union {
        struct { uint16_t ebuf[NBKT * BCAP]; int brun[NBKT], gbase[NBKT]; } sc;  // 16.5 KB
        struct { unsigned int cnt[CPB / 4]; int lhist[HBINS]; int ltot, lrun, gbase; } ct;  // 33.8 KB
        struct { uint32_t s[CAP]; int ls[HBINS]; int sT, sScnt; } so;            // 33.8 KB
    } u;
    int t = threadIdx.x;

    // ---------- phase 1: scatter (radix partition into per-(batch,bucket) lists) ----------
    for (int task = blockIdx.x; task < SCB * BATCH; task += GRID) {
        int b = task & 15;
        int chunk = task >> 4;
        if (t < NBKT) u.sc.brun[t] = 0;
        __syncthreads();
        const float* cb = coords + (size_t)b * NPTS * 3;
        int q0 = chunk * SCQ + t;
#pragma unroll
        for (int p = 0; p < 2; ++p) {
            int q = q0 + p * MT;
            if (q >= QPTS) continue;
            uint32_t di[4];
            didx4_of(cb, q, di);
#pragma unroll
            for (int uu = 0; uu < 4; ++uu) {
                uint32_t d = di[uu];
                if (d == (uint32_t)VOFF) {
                    atomicAdd(&meta[b * 8 + M_ORIGIN], 1);  // rare (~254/batch)
                } else {
                    uint32_t bk = bkt_of(d);
                    int pos = atomicAdd(&u.sc.brun[bk], 1);
                    if (pos < BCAP)
                        u.sc.ebuf[(bk << 7) + pos] = (uint16_t)(((d >> 15) << 9) | (d & 511u));
                }
            }
        }
        __syncthreads();
        if (t < NBKT) {
            int c = u.sc.brun[t] < BCAP ? u.sc.brun[t] : BCAP;  // mean 32; 128 = +17 sigma
            u.sc.brun[t] = c;
            u.sc.gbase[t] = atomicAdd(&cursor[b * NBKT + t], c);
        }
        __syncthreads();
        uint16_t* lb = lists + (size_t)b * NBKT * CAPL;
#pragma unroll
        for (int k = 0; k < NBKT * BCAP / (8 * MT); ++k) {  // 4 iters
            int s8 = (t + k * MT) * 8;
            int bk = s8 >> 7;
            int i0 = s8 & (BCAP - 1);
            int n = u.sc.brun[bk];
            if (i0 < n) {
                usvec8 v = *(const usvec8*)&u.sc.ebuf[s8];  // ds_read_b128
                int g0 = u.sc.gbase[bk] + i0;
#pragma unroll
                for (int j = 0; j < 8; ++j) {
                    int gi = g0 + j;
                    if (i0 + j < n && gi < CAPL) lb[bk * CAPL + gi] = v[j];
                }
            }
        }
        __syncthreads();  // flush done before next task resets brun/ebuf
    }
    grid_barrier(&bar[0]);

    // ---------- phase 2: count (one (batch,bucket) per block; GRID == NBKT*BATCH) ----------
    {
        int b = blockIdx.x & 15;
        uint32_t bkt = (uint32_t)(blockIdx.x >> 4);
        for (int i = t; i < CPB / 4; i += MT) u.ct.cnt[i] = 0;
        u.ct.lhist[t] = 0;
        if (t == 0) { u.ct.ltot = 0; u.ct.lrun = 0; }
        __syncthreads();
        const uint16_t* list = lists + ((size_t)b * NBKT + bkt) * CAPL;
        int n = cursor[b * NBKT + bkt];
        if (n > CAPL) n = CAPL;
        for (int i = t; i < n; i += MT) {
            uint32_t e = list[i];  // (A<<9)|C
            atomicAdd(&u.ct.cnt[e >> 2], 1u << ((e & 3u) * 8u));  // fire-and-forget LDS atomic
        }
        __syncthreads();
        int mycnt = 0;
        for (int i = t; i < CPB / 4; i += MT) {
            unsigned int w = u.ct.cnt[i];
            if (!w) continue;
#pragma unroll
            for (int j = 0; j < 4; ++j) {
                unsigned int c = (w >> (j * 8)) & 0xFFu;
                if (c) { atomicAdd(&u.ct.lhist[c], 1); ++mycnt; }
            }
        }
        if (mycnt) atomicAdd(&u.ct.ltot, mycnt);
        __syncthreads();
        if (t == 0) u.ct.gbase = atomicAdd(&ccur[b], u.ct.ltot);
        if (u.ct.lhist[t]) atomicAdd(&hist[b * HBINS + t], u.ct.lhist[t]);
        __syncthreads();
        uint32_t* cmp = compact + (size_t)b * CCAP;
        for (int i = t; i < CPB / 4; i += MT) {
            unsigned int w = u.ct.cnt[i];
            if (!w) continue;
#pragma unroll
            for (int j = 0; j < 4; ++j) {
                unsigned int c = (w >> (j * 8)) & 0xFFu;
                if (c) {
                    uint32_t local = (uint32_t)i * 4u + (uint32_t)j;
                    uint32_t A = local >> 9, C = local & 511u, B = bkt ^ A;
                    uint32_t di = (A << 15) | (B << 9) | C;
                    int slot = atomicAdd(&u.ct.lrun, 1);
                    int idx = u.ct.gbase + slot;
                    if (idx < CCAP) cmp[idx] = ((255u - c) << DBITS) | di;
                }
            }
        }
    }
    grid_barrier(&bar[1]);

    // ---------- phase 3: sortrank (blocks 0..15 only) ----------
    if (blockIdx.x < BATCH) {
        int b = blockIdx.x;
        int oc = meta[b * 8 + M_ORIGIN];
        int ocl = oc > 255 ? 255 : oc;  // origin = unique top cell (~254 vs ~35); rank-safe
        if (t == 0) { u.so.sT = 1; u.so.sScnt = 0; }
        u.so.ls[t] = (t >= 1 ? hist[b * HBINS + t] : 0) + ((oc > 0 && t == ocl) ? 1 : 0);
        __syncthreads();
        for (int off = 1; off < HBINS; off <<= 1) {
            int v = (t + off < HBINS) ? u.so.ls[t + off] : 0;
            __syncthreads();
            u.so.ls[t] += v;
            __syncthreads();
        }
        int U = u.so.ls[1];
        int mode = (U > KTOP) ? 1 : 0;
        if (mode && t >= 1 && u.so.ls[t] >= KTOP && (t == HBINS - 1 || u.so.ls[t + 1] < KTOP))
            u.so.sT = t;  // unique such t
        __syncthreads();
        uint32_t T = mode ? (uint32_t)u.so.sT : 1u;
        uint32_t maxtop = 255u - T;  // keep entries with count >= T
        int n = ccur[b];
        if (n > CCAP) n = CCAP;
        const uint32_t* cmp = compact + (size_t)b * CCAP;
        for (int i = t; i < n; i += MT) {
            uint32_t e = cmp[i];
            if (!mode || (e >> DBITS) <= maxtop) {
                uint32_t key = mode ? e : (e & (DSIZE - 1u));  // mode0: rank by di only
                int idx = atomicAdd(&u.so.sScnt, 1);
                if (idx < CAP) u.so.s[idx] = key;
            }
        }
        if (t == 0 && oc > 0) {  // inject origin entry
            uint32_t c = (uint32_t)ocl;
            if (!mode || c >= T) {
                uint32_t key = mode ? (((255u - c) << DBITS) | (uint32_t)VOFF) : (uint32_t)VOFF;
                int idx = atomicAdd(&u.so.sScnt, 1);
                if (idx < CAP) u.so.s[idx] = key;
            }
        }
        __syncthreads();
        int nk = u.so.sScnt < CAP ? u.so.sScnt : CAP;
        int P = 2;
        while (P < nk) P <<= 1;
        for (int i = nk + t; i < P; i += MT) u.so.s[i] = 0xFFFFFFFFu;  // real keys < 2^30
        __syncthreads();
        for (int k = 2; k <= P; k <<= 1) {
            for (int j = k >> 1; j > 0; j >>= 1) {
                for (int i = t; i < P; i += MT) {
                    int l = i ^ j;
                    if (l > i) {
                        uint32_t a = u.so.s[i], c2 = u.so.s[l];
                        bool asc = ((i & k) == 0);
                        if ((asc && a > c2) || (!asc && a < c2)) { u.so.s[i] = c2; u.so.s[l] = a; }
                    }
                }
                __syncthreads();
            }
        }
        int nsel = mode ? (nk < KTOP ? nk : KTOP) : nk;  // mode0: nk = U <= 512
        unsigned int* wb = winners + (size_t)b * WSIZE;
        for (int j = t; j < nsel; j += MT) {
            uint32_t di = u.so.s[j] & (DSIZE - 1u);
            uint32_t ins = (di << 9) | (uint32_t)j;  // 30 bits, != WEMPTY
            uint32_t h = (di * 0x9E3779B1u) >> (32 - WBITS);
            while (atomicCAS(&wb[h], WEMPTY, ins) != WEMPTY) h = (h + 1) & WMASK;
        }
    }
    grid_barrier(&bar[2]);

    // ---------- phase 4: label ----------
    for (int task = blockIdx.x; task < CHQ * BATCH; task += GRID) {
        int b = task & 15;
        int q = (task >> 4) * 256 + t;
        if (q >= QPTS) continue;
        uint32_t di[4];
        didx4_of(coords + (size_t)b * NPTS * 3, q, di);
        const unsigned int* wb = winners + (size_t)b * WSIZE;
        int r[4];
#pragma unroll
        for (int uu = 0; uu < 4; ++uu) {
            uint32_t h = (di[uu] * 0x9E3779B1u) >> (32 - WBITS);
            int rr = -1;
            while (true) {
                unsigned int w = wb[h];
                if (w == WEMPTY) break;
                if ((w >> 9) == di[uu]) { rr = (int)(w & 0x1FFu); break; }
                h = (h + 1) & WMASK;
            }
            r[uu] = rr;
        }
        ivec4 r4 = {r[0], r[1], r[2], r[3]};
        __builtin_nontemporal_store(r4, (ivec4*)(out + (size_t)b * NPTS + (size_t)q * 4));
    }
}

extern "C" void kernel_launch(void* const* d_in, const int* in_sizes, int n_in,
                              void* d_out, int out_size, void* d_ws, size_t ws_size,
                              hipStream_t stream) {
    const float* coords = (const float*)d_in[0];
    int* out = (int*)d_out;
    char* ws = (char*)d_ws;

    size_t off = 0;
    uint16_t* lists = (uint16_t*)(ws + off);           off += (size_t)BATCH * NBKT * CAPL * 2;  // 32 MB
    uint32_t* compact = (uint32_t*)(ws + off);         off += (size_t)BATCH * CCAP * 4;         // 16 MB
    int* cursor = (int*)(ws + off);                    off += (size_t)BATCH * NBKT * 4;         // 4 KB
    int* ccur = (int*)(ws + off);                      off += (size_t)BATCH * 4;                // 64 B
    int* hist = (int*)(ws + off);                      off += (size_t)BATCH * HBINS * 4;        // 16 KB
    int* meta = (int*)(ws + off);                      off += (size_t)BATCH * 8 * 4;            // 512 B
    int* bar = (int*)(ws + off);                       off += 8 * 4;                            // 32 B
    unsigned int* winners = (unsigned int*)(ws + off); off += (size_t)BATCH * WSIZE * 4;        // 128 KB

    // cursor..bar contiguous ints (NZERO); winners 0xFF. Re-run every launch.
    init_kernel<<<(BATCH * WSIZE + 255) / 256, 256, 0, stream>>>(cursor, winners);

    mega_kernel<<<GRID, MT, 0, stream>>>(coords, lists, cursor, meta, hist, compact, ccur,
                                         winners, bar, out);
}

// Round 12
// 140.412 us; speedup vs baseline: 18.3740x; 18.3740x over previous
//
#include <hip/hip_runtime.h>
#include <stdint.h>

#define BATCH 16
#define NPTS 500000
#define QPTS (NPTS / 4)        // 125000 quads
#define DBITS 21
#define DSIZE (1u << DBITS)
#define VOFF 969696            // di = vid + VOFF in [0, 2^21)
#define HBINS 256
#define CAP 8192
#define KTOP 512
#define NBKT 64
#define CPB 32768              // cells per bucket
#define SCT 256                // scatter block threads
#define SCQ 512                // quads per scatter chunk (2048 points)
#define SCB ((QPTS + SCQ - 1) / SCQ)   // 245 chunks per batch
#define BCAP 96                // list slot per (bucket,chunk): mean 32, +10 sigma
#define CCB 3072               // compact cap per (batch,bucket): mean ~1700, +10 sigma
#define CHQ ((QPTS + 255) / 256)       // 489 label chunks per batch
#define WBITS 11
#define WSIZE (1 << WBITS)
#define WMASK (WSIZE - 1)
#define WEMPTY 0xFFFFFFFFu

// origin cell: 8x volume (trunc-toward-zero), ~254 points > uint8 -> special-cased in count
#define OA (VOFF >> 15)                 // 29
#define OBKT (OA ^ ((VOFF >> 9) & 63))  // 56
#define OLOC ((OA << 9) | (VOFF & 511)) // 15328 = its entry value

typedef int ivec4 __attribute__((ext_vector_type(4)));
typedef unsigned short usvec8 __attribute__((ext_vector_type(8)));

// Must match JAX/np exactly: IEEE f32 divide (NOT *5.0f), trunc-toward-zero cast.
__device__ __forceinline__ uint32_t didx_of(float x, float y, float z) {
    int vx = (int)(x / 0.2f);
    int vy = (int)(y / 0.2f);
    int vz = (int)(z / 0.2f);
    int di = vx * 10000 + vy * 100 + vz + VOFF;
    return (uint32_t)di & (DSIZE - 1u);  // mask = memory safety only; unreachable (9.6 sigma)
}

__device__ __forceinline__ void didx4_of(const float* base, int q, uint32_t di[4]) {
    const float4* cp = (const float4*)(base) + (size_t)q * 3;
    float4 f0 = cp[0], f1 = cp[1], f2 = cp[2];
    di[0] = didx_of(f0.x, f0.y, f0.z);
    di[1] = didx_of(f0.w, f1.x, f1.y);
    di[2] = didx_of(f1.z, f1.w, f2.x);
    di[3] = didx_of(f2.y, f2.z, f2.w);
}

__device__ __forceinline__ uint32_t bkt_of(uint32_t d) {
    return ((d >> 15) ^ (d >> 9)) & 63u;   // A ^ B: decorrelates Gaussian vx alignment
}

// Radix partition into FIXED per-(bucket,chunk) slots. No global atomics, no init needed:
// everything read downstream is written here (counts byte per slot tells the reader n).
__global__ void __launch_bounds__(SCT) scatter_kernel(const float* __restrict__ coords,
                                                      uint16_t* __restrict__ lists,
                                                      uint8_t* __restrict__ cnts) {
    __shared__ uint16_t ebuf[NBKT * BCAP];  // 12 KB
    __shared__ int brun[NBKT];
    int id = blockIdx.x;
    int b = id & 15;
    int chunk = id >> 4;
    int t = threadIdx.x;
    if (t < NBKT) brun[t] = 0;
    __syncthreads();
    const float* cb = coords + (size_t)b * NPTS * 3;
    int q0 = chunk * SCQ + t;
#pragma unroll
    for (int p = 0; p < 2; ++p) {
        int q = q0 + p * SCT;
        if (q >= QPTS) continue;
        uint32_t di[4];
        didx4_of(cb, q, di);
#pragma unroll
        for (int u = 0; u < 4; ++u) {
            uint32_t d = di[u];
            uint32_t bk = bkt_of(d);
            int pos = atomicAdd(&brun[bk], 1);  // returning LDS atomic
            if (pos < BCAP)
                ebuf[bk * BCAP + pos] = (uint16_t)(((d >> 15) << 9) | (d & 511u));
        }
    }
    __syncthreads();
    // flush: 4 threads per bucket, 3 x 16B granules each (96 u16 total per bucket)
    int bk = t >> 2;
    int g0 = (t & 3) * 3;
    int n = brun[bk] < BCAP ? brun[bk] : BCAP;
    uint16_t* dst = lists + (((size_t)b * NBKT + bk) * SCB + chunk) * BCAP;
#pragma unroll
    for (int g = g0; g < g0 + 3; ++g) {
        if (g * 8 < n)  // granule may carry garbage past n; reader stops at n
            *(usvec8*)&dst[g * 8] = *(const usvec8*)&ebuf[bk * BCAP + g * 8];
    }
    if (t < NBKT) cnts[((size_t)b * NBKT + t) * 256 + chunk] = (uint8_t)(brun[t] < BCAP ? brun[t] : BCAP);
}

// One block per (batch,bucket): LDS byte-count 32768 cells, origin cell in a 32-bit
// LDS counter (clamped 255 at emit; unique top cell so ranking unaffected). Emits
// per-bucket compact entries + per-bucket local histogram. No zeroed global state.
__global__ void __launch_bounds__(256) count_kernel(const uint16_t* __restrict__ lists,
                                                    const uint8_t* __restrict__ cnts,
                                                    uint32_t* __restrict__ compact,
                                                    int* __restrict__ ccnt,
                                                    uint16_t* __restrict__ histb) {
    __shared__ unsigned int cnt[CPB / 4];  // 32 KB
    __shared__ int lhist[HBINS];
    __shared__ uint8_t nbuf[256];
    __shared__ int lrun, sOrig;
    int id = blockIdx.x;
    int b = id & 15;
    uint32_t bkt = (uint32_t)(id >> 4);
    int t = threadIdx.x;
    for (int i = t; i < CPB / 4; i += 256) cnt[i] = 0;
    lhist[t] = 0;
    if (t == 0) { lrun = 0; sOrig = 0; }
    nbuf[t] = (t < SCB) ? cnts[((size_t)b * NBKT + bkt) * 256 + t] : 0;
    __syncthreads();
    const uint16_t* base = lists + ((size_t)b * NBKT + bkt) * SCB * BCAP;
    bool isO = (bkt == (uint32_t)OBKT);
    // 4 threads per chunk, 3 granules each; 64 chunks per round, 4 rounds
#pragma unroll
    for (int r = 0; r < 4; ++r) {
        int c = r * 64 + (t >> 2);
        if (c >= SCB) continue;
        int n = nbuf[c];
        int gb = (t & 3) * 3;
#pragma unroll
        for (int g = gb; g < gb + 3; ++g) {
            int i0 = g * 8;
            if (i0 >= n) continue;
            usvec8 v = *(const usvec8*)&base[c * BCAP + i0];
            int lim = n - i0;
#pragma unroll
            for (int j = 0; j < 8; ++j) {
                if (j >= lim) break;
                uint32_t e = v[j];
                if (isO && e == (uint32_t)OLOC)
                    atomicAdd(&sOrig, 1);
                else
                    atomicAdd(&cnt[e >> 2], 1u << ((e & 3u) * 8u));  // fire-and-forget
            }
        }
    }
    __syncthreads();
    if (isO && t == 0 && sOrig > 0) {
        int oc = sOrig > 255 ? 255 : sOrig;  // 2nd-max cell ~35: clamp is rank-safe
        ((uint8_t*)cnt)[OLOC] = (uint8_t)oc;  // ds_write_b8 into the byte grid
    }
    __syncthreads();
    uint32_t* cmp = compact + ((size_t)b * NBKT + bkt) * CCB;
    for (int i = t; i < CPB / 4; i += 256) {
        unsigned int w = cnt[i];
        if (!w) continue;
#pragma unroll
        for (int j = 0; j < 4; ++j) {
            unsigned int c = (w >> (j * 8)) & 0xFFu;
            if (c) {
                atomicAdd(&lhist[c], 1);
                int slot = atomicAdd(&lrun, 1);
                if (slot < CCB) {
                    uint32_t local = (uint32_t)i * 4u + (uint32_t)j;
                    uint32_t A = local >> 9, C = local & 511u, B = bkt ^ A;
                    uint32_t di = (A << 15) | (B << 9) | C;
                    cmp[slot] = ((255u - c) << DBITS) | di;
                }
            }
        }
    }
    __syncthreads();
    histb[((size_t)b * NBKT + bkt) * HBINS + t] = (uint16_t)lhist[t];  // bins <= 32768
    if (t == 0) ccnt[b * NBKT + (int)bkt] = lrun < CCB ? lrun : CCB;
}

// Per batch: fill winners, sum 64 local hists, suffix-scan -> T, filter, bitonic sort,
// insert winner hash entries. All state written before read within this kernel.
__global__ void __launch_bounds__(1024) sortrank_kernel(const uint32_t* __restrict__ compact,
                                                        const int* __restrict__ ccnt,
                                                        const uint16_t* __restrict__ histb,
                                                        unsigned int* __restrict__ winners) {
    __shared__ uint32_t s[CAP];  // 32 KB
    __shared__ int ls[HBINS];
    __shared__ int lc[NBKT];
    __shared__ int sT, sScnt;
    int b = blockIdx.x;
    int t = threadIdx.x;
    unsigned int* wb = winners + (size_t)b * WSIZE;
    for (int i = t; i < WSIZE; i += 1024) wb[i] = WEMPTY;  // in-kernel init
    if (t == 0) { sT = 1; sScnt = 0; }
    if (t < NBKT) lc[t] = ccnt[b * NBKT + t];
    if (t < HBINS) {
        int sum = 0;
        for (int k = 0; k < NBKT; ++k) sum += histb[((size_t)b * NBKT + k) * HBINS + t];
        ls[t] = (t >= 1) ? sum : 0;
    }
    __syncthreads();
    for (int off = 1; off < HBINS; off <<= 1) {  // suffix scan; ALL threads at barriers
        int v = 0;
        if (t < HBINS && t + off < HBINS) v = ls[t + off];
        __syncthreads();
        if (t < HBINS) ls[t] += v;
        __syncthreads();
    }
    int U = ls[1];
    int mode = (U > KTOP) ? 1 : 0;
    if (mode && t >= 1 && t < HBINS && ls[t] >= KTOP && (t == HBINS - 1 || ls[t + 1] < KTOP))
        sT = t;  // unique such t
    __syncthreads();
    uint32_t T = mode ? (uint32_t)sT : 1u;
    uint32_t maxtop = 255u - T;  // keep entries with count >= T
    for (int bk = 0; bk < NBKT; ++bk) {
        const uint32_t* cmp = compact + ((size_t)b * NBKT + bk) * CCB;
        int n = lc[bk];
        for (int i = t; i < n; i += 1024) {
            uint32_t e = cmp[i];
            if (!mode || (e >> DBITS) <= maxtop) {
                uint32_t key = mode ? e : (e & (DSIZE - 1u));  // mode0: rank by di only
                int idx = atomicAdd(&sScnt, 1);
                if (idx < CAP) s[idx] = key;
            }
        }
    }
    __syncthreads();
    int nk = sScnt < CAP ? sScnt : CAP;
    int P = 2;
    while (P < nk) P <<= 1;
    for (int i = nk + t; i < P; i += 1024) s[i] = 0xFFFFFFFFu;  // real keys < 2^30
    __syncthreads();
    for (int k = 2; k <= P; k <<= 1) {
        for (int j = k >> 1; j > 0; j >>= 1) {
            for (int i = t; i < P; i += 1024) {
                int l = i ^ j;
                if (l > i) {
                    uint32_t a = s[i], c2 = s[l];
                    bool asc = ((i & k) == 0);
                    if ((asc && a > c2) || (!asc && a < c2)) { s[i] = c2; s[l] = a; }
                }
            }
            __syncthreads();
        }
    }
    int nsel = mode ? (nk < KTOP ? nk : KTOP) : nk;  // mode0: nk = U <= 512
    for (int j = t; j < nsel; j += 1024) {
        uint32_t di = s[j] & (DSIZE - 1u);
        uint32_t ins = (di << 9) | (uint32_t)j;  // 30 bits, != WEMPTY
        uint32_t h = (di * 0x9E3779B1u) >> (32 - WBITS);
        while (atomicCAS(&wb[h], WEMPTY, ins) != WEMPTY) h = (h + 1) & WMASK;
    }
}

// Recompute didx per point (coords L3-hot); probe 8 KB winner hash; -1 on first empty.
__global__ void label_kernel(const float* __restrict__ coords,
                             const unsigned int* __restrict__ winners,
                             int* __restrict__ out) {
    int id = blockIdx.x;
    int b = id & 15;
    int q = (id >> 4) * 256 + threadIdx.x;
    if (q >= QPTS) return;
    uint32_t di[4];
    didx4_of(coords + (size_t)b * NPTS * 3, q, di);
    const unsigned int* wb = winners + (size_t)b * WSIZE;
    int r[4];
#pragma unroll
    for (int u = 0; u < 4; ++u) {
        uint32_t h = (di[u] * 0x9E3779B1u) >> (32 - WBITS);
        int rr = -1;
        while (true) {
            unsigned int w = wb[h];
            if (w == WEMPTY) break;
            if ((w >> 9) == di[u]) { rr = (int)(w & 0x1FFu); break; }
            h = (h + 1) & WMASK;
        }
        r[u] = rr;
    }
    ivec4 r4 = {r[0], r[1], r[2], r[3]};
    __builtin_nontemporal_store(r4, (ivec4*)(out + (size_t)b * NPTS + (size_t)q * 4));
}

extern "C" void kernel_launch(void* const* d_in, const int* in_sizes, int n_in,
                              void* d_out, int out_size, void* d_ws, size_t ws_size,
                              hipStream_t stream) {
    const float* coords = (const float*)d_in[0];
    int* out = (int*)d_out;
    char* ws = (char*)d_ws;

    size_t off = 0;
    uint16_t* lists = (uint16_t*)(ws + off);   off += (size_t)BATCH * NBKT * SCB * BCAP * 2;  // 48.2 MB
    uint32_t* compact = (uint32_t*)(ws + off); off += (size_t)BATCH * NBKT * CCB * 4;         // 12.6 MB
    uint8_t* cnts = (uint8_t*)(ws + off);      off += (size_t)BATCH * NBKT * 256;             // 256 KB
    uint16_t* histb = (uint16_t*)(ws + off);   off += (size_t)BATCH * NBKT * HBINS * 2;       // 512 KB
    int* ccnt = (int*)(ws + off);              off += (size_t)BATCH * NBKT * 4;               // 4 KB
    unsigned int* winners = (unsigned int*)(ws + off); off += (size_t)BATCH * WSIZE * 4;      // 128 KB

    // NO init dispatch: every word read by a kernel is written earlier in THIS launch.
    scatter_kernel<<<SCB * BATCH, SCT, 0, stream>>>(coords, lists, cnts);
    count_kernel<<<NBKT * BATCH, 256, 0, stream>>>(lists, cnts, compact, ccnt, histb);
    sortrank_kernel<<<BATCH, 1024, 0, stream>>>(compact, ccnt, histb, winners);
    label_kernel<<<CHQ * BATCH, 256, 0, stream>>>(coords, winners, out);
}

// Round 13
// 110.525 us; speedup vs baseline: 23.3425x; 1.2704x over previous
//
#include <hip/hip_runtime.h>
#include <stdint.h>

#define BATCH 16
#define NPTS 500000
#define QPTS (NPTS / 4)        // 125000 quads
#define DBITS 21
#define DSIZE (1u << DBITS)
#define VOFF 969696            // di = vid + VOFF in [0, 2^21)
#define HBINS 256
#define CAP 8192
#define KTOP 512
#define NBKT 64
#define CPB 32768              // cells per bucket
#define SCT 256                // scatter block threads
#define SCQ 512                // quads per scatter chunk (2048 points)
#define SCB ((QPTS + SCQ - 1) / SCQ)   // 245 chunks per batch
#define BCAP 96                // list slot per (bucket,chunk): mean 32, +10 sigma
#define CCB 3072               // compact cap per (batch,bucket): mean ~1700, +10 sigma
#define CHQ ((QPTS + 255) / 256)       // 489 label chunks per batch
#define WBITS 11
#define WSIZE (1 << WBITS)
#define WMASK (WSIZE - 1)
#define WEMPTY 0xFFFFFFFFu

// origin cell: 8x volume (trunc-toward-zero), ~254 points > uint8 -> special-cased in count
#define OA (VOFF >> 15)                 // 29
#define OBKT (OA ^ ((VOFF >> 9) & 63))  // 56
#define OLOC ((OA << 9) | (VOFF & 511)) // 15328 = its entry value

typedef int ivec4 __attribute__((ext_vector_type(4)));
typedef unsigned short usvec8 __attribute__((ext_vector_type(8)));

// Must match JAX/np exactly: IEEE f32 divide (NOT *5.0f), trunc-toward-zero cast.
__device__ __forceinline__ uint32_t didx_of(float x, float y, float z) {
    int vx = (int)(x / 0.2f);
    int vy = (int)(y / 0.2f);
    int vz = (int)(z / 0.2f);
    int di = vx * 10000 + vy * 100 + vz + VOFF;
    return (uint32_t)di & (DSIZE - 1u);  // mask = memory safety only; unreachable (9.6 sigma)
}

__device__ __forceinline__ void didx4_of(const float* base, int q, uint32_t di[4]) {
    const float4* cp = (const float4*)(base) + (size_t)q * 3;
    float4 f0 = cp[0], f1 = cp[1], f2 = cp[2];
    di[0] = didx_of(f0.x, f0.y, f0.z);
    di[1] = didx_of(f0.w, f1.x, f1.y);
    di[2] = didx_of(f1.z, f1.w, f2.x);
    di[3] = didx_of(f2.y, f2.z, f2.w);
}

__device__ __forceinline__ uint32_t bkt_of(uint32_t d) {
    return ((d >> 15) ^ (d >> 9)) & 63u;   // A ^ B: decorrelates Gaussian vx alignment
}

// Radix partition into FIXED per-(bucket,chunk) slots. No global atomics, no init needed:
// everything read downstream is written here (counts byte per slot tells the reader n).
__global__ void __launch_bounds__(SCT) scatter_kernel(const float* __restrict__ coords,
                                                      uint16_t* __restrict__ lists,
                                                      uint8_t* __restrict__ cnts) {
    __shared__ uint16_t ebuf[NBKT * BCAP];  // 12 KB
    __shared__ int brun[NBKT];
    int id = blockIdx.x;
    int b = id & 15;
    int chunk = id >> 4;
    int t = threadIdx.x;
    if (t < NBKT) brun[t] = 0;
    __syncthreads();
    const float* cb = coords + (size_t)b * NPTS * 3;
    int q0 = chunk * SCQ + t;
#pragma unroll
    for (int p = 0; p < 2; ++p) {
        int q = q0 + p * SCT;
        if (q >= QPTS) continue;
        uint32_t di[4];
        didx4_of(cb, q, di);
#pragma unroll
        for (int u = 0; u < 4; ++u) {
            uint32_t d = di[u];
            uint32_t bk = bkt_of(d);
            int pos = atomicAdd(&brun[bk], 1);  // returning LDS atomic
            if (pos < BCAP)
                ebuf[bk * BCAP + pos] = (uint16_t)(((d >> 15) << 9) | (d & 511u));
        }
    }
    __syncthreads();
    // flush: 4 threads per bucket, 3 x 16B granules each (96 u16 total per bucket)
    int bk = t >> 2;
    int g0 = (t & 3) * 3;
    int n = brun[bk] < BCAP ? brun[bk] : BCAP;
    uint16_t* dst = lists + (((size_t)b * NBKT + bk) * SCB + chunk) * BCAP;
#pragma unroll
    for (int g = g0; g < g0 + 3; ++g) {
        if (g * 8 < n)  // granule may carry garbage past n; reader stops at n
            *(usvec8*)&dst[g * 8] = *(const usvec8*)&ebuf[bk * BCAP + g * 8];
    }
    if (t < NBKT) cnts[((size_t)b * NBKT + t) * 256 + chunk] = (uint8_t)(brun[t] < BCAP ? brun[t] : BCAP);
}

// One block per (batch,bucket): LDS byte-count 32768 cells, origin cell in a 32-bit
// LDS counter (clamped 255 at emit; unique top cell so ranking unaffected). Emits
// per-bucket compact entries + per-bucket local histogram. No zeroed global state.
__global__ void __launch_bounds__(256) count_kernel(const uint16_t* __restrict__ lists,
                                                    const uint8_t* __restrict__ cnts,
                                                    uint32_t* __restrict__ compact,
                                                    int* __restrict__ ccnt,
                                                    uint16_t* __restrict__ histb) {
    __shared__ unsigned int cnt[CPB / 4];  // 32 KB
    __shared__ int lhist[HBINS];
    __shared__ uint8_t nbuf[256];
    __shared__ int lrun, sOrig;
    int id = blockIdx.x;
    int b = id & 15;
    uint32_t bkt = (uint32_t)(id >> 4);
    int t = threadIdx.x;
    for (int i = t; i < CPB / 4; i += 256) cnt[i] = 0;
    lhist[t] = 0;
    if (t == 0) { lrun = 0; sOrig = 0; }
    nbuf[t] = (t < SCB) ? cnts[((size_t)b * NBKT + bkt) * 256 + t] : 0;
    __syncthreads();
    const uint16_t* base = lists + ((size_t)b * NBKT + bkt) * SCB * BCAP;
    bool isO = (bkt == (uint32_t)OBKT);
    // 4 threads per chunk, 3 granules each; 64 chunks per round, 4 rounds
#pragma unroll
    for (int r = 0; r < 4; ++r) {
        int c = r * 64 + (t >> 2);
        if (c >= SCB) continue;
        int n = nbuf[c];
        int gb = (t & 3) * 3;
#pragma unroll
        for (int g = gb; g < gb + 3; ++g) {
            int i0 = g * 8;
            if (i0 >= n) continue;
            usvec8 v = *(const usvec8*)&base[c * BCAP + i0];
            int lim = n - i0;
#pragma unroll
            for (int j = 0; j < 8; ++j) {
                if (j >= lim) break;
                uint32_t e = v[j];
                if (isO && e == (uint32_t)OLOC)
                    atomicAdd(&sOrig, 1);
                else
                    atomicAdd(&cnt[e >> 2], 1u << ((e & 3u) * 8u));  // fire-and-forget
            }
        }
    }
    __syncthreads();
    if (isO && t == 0 && sOrig > 0) {
        int oc = sOrig > 255 ? 255 : sOrig;  // 2nd-max cell ~35: clamp is rank-safe
        ((uint8_t*)cnt)[OLOC] = (uint8_t)oc;  // ds_write_b8 into the byte grid
    }
    __syncthreads();
    uint32_t* cmp = compact + ((size_t)b * NBKT + bkt) * CCB;
    for (int i = t; i < CPB / 4; i += 256) {
        unsigned int w = cnt[i];
        if (!w) continue;
#pragma unroll
        for (int j = 0; j < 4; ++j) {
            unsigned int c = (w >> (j * 8)) & 0xFFu;
            if (c) {
                atomicAdd(&lhist[c], 1);
                int slot = atomicAdd(&lrun, 1);
                if (slot < CCB) {
                    uint32_t local = (uint32_t)i * 4u + (uint32_t)j;
                    uint32_t A = local >> 9, C = local & 511u, B = bkt ^ A;
                    uint32_t di = (A << 15) | (B << 9) | C;
                    cmp[slot] = ((255u - c) << DBITS) | di;
                }
            }
        }
    }
    __syncthreads();
    histb[((size_t)b * NBKT + bkt) * HBINS + t] = (uint16_t)lhist[t];  // bins <= 32768
    if (t == 0) ccnt[b * NBKT + (int)bkt] = lrun < CCB ? lrun : CCB;
}

// Per batch: fill winners, wave-parallel hist sum, suffix scan -> T, flattened-padded
// filter (independent uint4 loads, fully pipelined), rank-by-counting (LDS broadcast,
// zero barriers), winner-hash insert. Replaces serial-bucket filter + 55-barrier bitonic.
__global__ void __launch_bounds__(1024) sortrank_kernel(const uint32_t* __restrict__ compact,
                                                        const int* __restrict__ ccnt,
                                                        const uint16_t* __restrict__ histb,
                                                        unsigned int* __restrict__ winners) {
    __shared__ uint32_t s[CAP];  // 32 KB
    __shared__ int ls[HBINS];
    __shared__ int lc[NBKT];
    __shared__ int sT, sScnt;
    int b = blockIdx.x;
    int t = threadIdx.x;
    unsigned int* wb = winners + (size_t)b * WSIZE;
    for (int i = t; i < WSIZE; i += 1024) wb[i] = WEMPTY;  // in-kernel init
    if (t == 0) { sT = 1; sScnt = 0; }
    if (t < NBKT) lc[t] = ccnt[b * NBKT + t];
    if (t < HBINS) ls[t] = 0;
    __syncthreads();
    // hist sum: 4 threads per bin, 16 buckets each (independent loads, LDS-atomic combine)
    {
        int bin = t & 255, grp = t >> 8;  // grp 0..3
        if (bin >= 1) {
            int sum = 0;
#pragma unroll
            for (int k = 0; k < 16; ++k)
                sum += histb[((size_t)b * NBKT + (grp * 16 + k)) * HBINS + bin];
            if (sum) atomicAdd(&ls[bin], sum);
        }
    }
    __syncthreads();
    for (int off = 1; off < HBINS; off <<= 1) {  // suffix scan; ALL threads at barriers
        int v = 0;
        if (t < HBINS && t + off < HBINS) v = ls[t + off];
        __syncthreads();
        if (t < HBINS) ls[t] += v;
        __syncthreads();
    }
    int U = ls[1];
    int mode = (U > KTOP) ? 1 : 0;
    if (mode && t >= 1 && t < HBINS && ls[t] >= KTOP && (t == HBINS - 1 || ls[t + 1] < KTOP))
        sT = t;  // unique such t
    __syncthreads();
    uint32_t T = mode ? (uint32_t)sT : 1u;
    uint32_t maxtop = 255u - T;  // keep entries with count >= T
    // flattened padded filter: uint4 loads over the whole per-batch compact space.
    // All iterations independent -> memory pipeline stays full (no serial bucket loop).
    const uint32_t* cmpb = compact + (size_t)b * NBKT * CCB;
    for (int i = t; i < NBKT * CCB / 4; i += 1024) {  // 48 iterations
        int f = i * 4;
        int bk = f / CCB;            // const-div -> magic multiply
        int rem = f - bk * CCB;
        int nv = lc[bk] - rem;       // valid elements among these 4 (may be <=0)
        if (nv <= 0) continue;
        uint4 v4 = *(const uint4*)&cmpb[f];
        uint32_t vv[4] = {v4.x, v4.y, v4.z, v4.w};
#pragma unroll
        for (int j = 0; j < 4; ++j) {
            if (j >= nv) break;
            uint32_t e = vv[j];
            if (!mode || (e >> DBITS) <= maxtop) {
                uint32_t key = mode ? e : (e & (DSIZE - 1u));  // mode0: rank by di only
                int idx = atomicAdd(&sScnt, 1);
                if (idx < CAP) s[idx] = key;
            }
        }
    }
    __syncthreads();
    int nk = sScnt < CAP ? sScnt : CAP;
    int nsel = mode ? (nk < KTOP ? nk : KTOP) : nk;  // mode0: nk = U <= 512
    // rank-by-counting: keys unique; rank = #{smaller}. LDS broadcast reads, no barriers.
    for (int j = t; j < nk; j += 1024) {
        uint32_t key = s[j];
        int r = 0;
#pragma unroll 4
        for (int i = 0; i < nk; ++i) r += (s[i] < key) ? 1 : 0;
        if (r < nsel) {
            uint32_t di = key & (DSIZE - 1u);
            uint32_t ins = (di << 9) | (uint32_t)r;  // 30 bits, != WEMPTY
            uint32_t h = (di * 0x9E3779B1u) >> (32 - WBITS);
            while (atomicCAS(&wb[h], WEMPTY, ins) != WEMPTY) h = (h + 1) & WMASK;
        }
    }
}

// Recompute didx per point (coords L3-hot); probe 8 KB winner hash; -1 on first empty.
__global__ void label_kernel(const float* __restrict__ coords,
                             const unsigned int* __restrict__ winners,
                             int* __restrict__ out) {
    int id = blockIdx.x;
    int b = id & 15;
    int q = (id >> 4) * 256 + threadIdx.x;
    if (q >= QPTS) return;
    uint32_t di[4];
    didx4_of(coords + (size_t)b * NPTS * 3, q, di);
    const unsigned int* wb = winners + (size_t)b * WSIZE;
    int r[4];
#pragma unroll
    for (int u = 0; u < 4; ++u) {
        uint32_t h = (di[u] * 0x9E3779B1u) >> (32 - WBITS);
        int rr = -1;
        while (true) {
            unsigned int w = wb[h];
            if (w == WEMPTY) break;
            if ((w >> 9) == di[u]) { rr = (int)(w & 0x1FFu); break; }
            h = (h + 1) & WMASK;
        }
        r[u] = rr;
    }
    ivec4 r4 = {r[0], r[1], r[2], r[3]};
    __builtin_nontemporal_store(r4, (ivec4*)(out + (size_t)b * NPTS + (size_t)q * 4));
}

extern "C" void kernel_launch(void* const* d_in, const int* in_sizes, int n_in,
                              void* d_out, int out_size, void* d_ws, size_t ws_size,
                              hipStream_t stream) {
    const float* coords = (const float*)d_in[0];
    int* out = (int*)d_out;
    char* ws = (char*)d_ws;

    size_t off = 0;
    uint16_t* lists = (uint16_t*)(ws + off);   off += (size_t)BATCH * NBKT * SCB * BCAP * 2;  // 48.2 MB
    uint32_t* compact = (uint32_t*)(ws + off); off += (size_t)BATCH * NBKT * CCB * 4;         // 12.6 MB
    uint8_t* cnts = (uint8_t*)(ws + off);      off += (size_t)BATCH * NBKT * 256;             // 256 KB
    uint16_t* histb = (uint16_t*)(ws + off);   off += (size_t)BATCH * NBKT * HBINS * 2;       // 512 KB
    int* ccnt = (int*)(ws + off);              off += (size_t)BATCH * NBKT * 4;               // 4 KB
    unsigned int* winners = (unsigned int*)(ws + off); off += (size_t)BATCH * WSIZE * 4;      // 128 KB

    // NO init dispatch: every word read by a kernel is written earlier in THIS launch.
    scatter_kernel<<<SCB * BATCH, SCT, 0, stream>>>(coords, lists, cnts);
    count_kernel<<<NBKT * BATCH, 256, 0, stream>>>(lists, cnts, compact, ccnt, histb);
    sortrank_kernel<<<BATCH, 1024, 0, stream>>>(compact, ccnt, histb, winners);
    label_kernel<<<CHQ * BATCH, 256, 0, stream>>>(coords, winners, out);
}

// Round 15
// 109.951 us; speedup vs baseline: 23.4643x; 1.0052x over previous
//
#include <hip/hip_runtime.h>
#include <stdint.h>

#define BATCH 16
#define NPTS 500000
#define QPTS (NPTS / 4)        // 125000 quads
#define DBITS 21
#define DSIZE (1u << DBITS)
#define VOFF 969696            // di = vid + VOFF in [0, 2^21)
#define HBINS 256
#define CAP 8192
#define KTOP 512
#define NBKT 64
#define CPB 32768              // cells per bucket
#define SCT 256                // scatter block threads
#define SCQ 512                // quads per scatter chunk (2048 points) — R13-proven
#define SCB ((QPTS + SCQ - 1) / SCQ)   // 245 chunks per batch
#define BCAP 96                // list slot per (bucket,chunk): mean 32, +11 sigma — R13-proven
#define CCB 3072               // compact cap per (batch,bucket): mean ~1700, +10 sigma
#define CHQ ((QPTS + 255) / 256)       // 489 label chunks per batch
#define WBITS 11
#define WSIZE (1 << WBITS)
#define WMASK (WSIZE - 1)
#define WEMPTY 0xFFFFFFFFu

// origin cell: 8x volume (trunc-toward-zero), ~254 points > uint8 -> special-cased in count
#define OA (VOFF >> 15)                 // 29
#define OBKT (OA ^ ((VOFF >> 9) & 63))  // 56
#define OLOC ((OA << 9) | (VOFF & 511)) // 15328 = its entry value

typedef int ivec4 __attribute__((ext_vector_type(4)));
typedef unsigned short usvec8 __attribute__((ext_vector_type(8)));

// Must match JAX/np exactly: IEEE f32 divide (NOT *5.0f — the reciprocal differs in
// trunc for ~dozens of boundary points), trunc-toward-zero cast.
__device__ __forceinline__ uint32_t didx_of(float x, float y, float z) {
    int vx = (int)(x / 0.2f);
    int vy = (int)(y / 0.2f);
    int vz = (int)(z / 0.2f);
    int di = vx * 10000 + vy * 100 + vz + VOFF;
    return (uint32_t)di & (DSIZE - 1u);  // mask = memory safety only; unreachable (9.6 sigma)
}

__device__ __forceinline__ void didx4_of(const float* base, int q, uint32_t di[4]) {
    const float4* cp = (const float4*)(base) + (size_t)q * 3;
    float4 f0 = cp[0], f1 = cp[1], f2 = cp[2];
    di[0] = didx_of(f0.x, f0.y, f0.z);
    di[1] = didx_of(f0.w, f1.x, f1.y);
    di[2] = didx_of(f1.z, f1.w, f2.x);
    di[3] = didx_of(f2.y, f2.z, f2.w);
}

__device__ __forceinline__ uint32_t bkt_of(uint32_t d) {
    return ((d >> 15) ^ (d >> 9)) & 63u;   // A ^ B: decorrelates Gaussian vx alignment
}

// R13 radix partition + ONE change: all 6 float4 loads hoisted before any compute,
// so the two quads' load latency overlaps (R13 serialized load->divide->LDS per quad).
__global__ void __launch_bounds__(SCT) scatter_kernel(const float* __restrict__ coords,
                                                      uint16_t* __restrict__ lists,
                                                      uint8_t* __restrict__ cnts) {
    __shared__ uint16_t ebuf[NBKT * BCAP];  // 12 KB
    __shared__ int brun[NBKT];
    int id = blockIdx.x;
    int b = id & 15;
    int chunk = id >> 4;
    int t = threadIdx.x;
    if (t < NBKT) brun[t] = 0;
    __syncthreads();
    const float4* cb4 = (const float4*)(coords + (size_t)b * NPTS * 3);
    int q0 = chunk * SCQ + t;
    int q1 = q0 + SCT;
    bool v0 = q0 < QPTS, v1 = q1 < QPTS;
    // ---- load phase: 6 independent float4 loads issued back-to-back
    float4 f[6];
    if (v0) {
        f[0] = cb4[(size_t)q0 * 3 + 0];
        f[1] = cb4[(size_t)q0 * 3 + 1];
        f[2] = cb4[(size_t)q0 * 3 + 2];
    }
    if (v1) {
        f[3] = cb4[(size_t)q1 * 3 + 0];
        f[4] = cb4[(size_t)q1 * 3 + 1];
        f[5] = cb4[(size_t)q1 * 3 + 2];
    }
    // ---- compute phase: 8 didx
    uint32_t di[8];
    if (v0) {
        di[0] = didx_of(f[0].x, f[0].y, f[0].z);
        di[1] = didx_of(f[0].w, f[1].x, f[1].y);
        di[2] = didx_of(f[1].z, f[1].w, f[2].x);
        di[3] = didx_of(f[2].y, f[2].z, f[2].w);
    }
    if (v1) {
        di[4] = didx_of(f[3].x, f[3].y, f[3].z);
        di[5] = didx_of(f[3].w, f[4].x, f[4].y);
        di[6] = didx_of(f[4].z, f[4].w, f[5].x);
        di[7] = didx_of(f[5].y, f[5].z, f[5].w);
    }
    // ---- staging phase: per-bucket LDS stacks
#pragma unroll
    for (int u = 0; u < 8; ++u) {
        if (u < 4 ? !v0 : !v1) continue;
        uint32_t d = di[u];
        uint32_t bk = bkt_of(d);
        int pos = atomicAdd(&brun[bk], 1);  // returning LDS atomic
        if (pos < BCAP)
            ebuf[bk * BCAP + pos] = (uint16_t)(((d >> 15) << 9) | (d & 511u));
    }
    __syncthreads();
    // flush: 4 threads per bucket, 3 x 16B granules each (96 u16 total per bucket)
    int bk = t >> 2;
    int g0 = (t & 3) * 3;
    int n = brun[bk] < BCAP ? brun[bk] : BCAP;
    uint16_t* dst = lists + (((size_t)b * NBKT + bk) * SCB + chunk) * BCAP;
#pragma unroll
    for (int g = g0; g < g0 + 3; ++g) {
        if (g * 8 < n)  // granule may carry garbage past n; reader stops at n
            *(usvec8*)&dst[g * 8] = *(const usvec8*)&ebuf[bk * BCAP + g * 8];
    }
    if (t < NBKT) cnts[((size_t)b * NBKT + t) * 256 + chunk] = (uint8_t)(brun[t] < BCAP ? brun[t] : BCAP);
}

// One block per (batch,bucket): LDS byte-count 32768 cells, origin cell in a 32-bit
// LDS counter (clamped 255 at emit; unique top cell so ranking unaffected). Emits
// per-bucket compact entries + per-bucket local histogram. No zeroed global state.
__global__ void __launch_bounds__(256) count_kernel(const uint16_t* __restrict__ lists,
                                                    const uint8_t* __restrict__ cnts,
                                                    uint32_t* __restrict__ compact,
                                                    int* __restrict__ ccnt,
                                                    uint16_t* __restrict__ histb) {
    __shared__ unsigned int cnt[CPB / 4];  // 32 KB
    __shared__ int lhist[HBINS];
    __shared__ uint8_t nbuf[256];
    __shared__ int lrun, sOrig;
    int id = blockIdx.x;
    int b = id & 15;
    uint32_t bkt = (uint32_t)(id >> 4);
    int t = threadIdx.x;
    for (int i = t; i < CPB / 4; i += 256) cnt[i] = 0;
    lhist[t] = 0;
    if (t == 0) { lrun = 0; sOrig = 0; }
    nbuf[t] = (t < SCB) ? cnts[((size_t)b * NBKT + bkt) * 256 + t] : 0;
    __syncthreads();
    const uint16_t* base = lists + ((size_t)b * NBKT + bkt) * SCB * BCAP;
    bool isO = (bkt == (uint32_t)OBKT);
    // 4 threads per chunk, 3 granules each; 64 chunks per round, 4 rounds
#pragma unroll
    for (int r = 0; r < 4; ++r) {
        int c = r * 64 + (t >> 2);
        if (c >= SCB) continue;
        int n = nbuf[c];
        int gb = (t & 3) * 3;
#pragma unroll
        for (int g = gb; g < gb + 3; ++g) {
            int i0 = g * 8;
            if (i0 >= n) continue;
            usvec8 v = *(const usvec8*)&base[c * BCAP + i0];
            int lim = n - i0;
#pragma unroll
            for (int j = 0; j < 8; ++j) {
                if (j >= lim) break;
                uint32_t e = v[j];
                if (isO && e == (uint32_t)OLOC)
                    atomicAdd(&sOrig, 1);
                else
                    atomicAdd(&cnt[e >> 2], 1u << ((e & 3u) * 8u));  // fire-and-forget
            }
        }
    }
    __syncthreads();
    if (isO && t == 0 && sOrig > 0) {
        int oc = sOrig > 255 ? 255 : sOrig;  // 2nd-max cell ~35: clamp is rank-safe
        ((uint8_t*)cnt)[OLOC] = (uint8_t)oc;  // ds_write_b8 into the byte grid
    }
    __syncthreads();
    uint32_t* cmp = compact + ((size_t)b * NBKT + bkt) * CCB;
    for (int i = t; i < CPB / 4; i += 256) {
        unsigned int w = cnt[i];
        if (!w) continue;
#pragma unroll
        for (int j = 0; j < 4; ++j) {
            unsigned int c = (w >> (j * 8)) & 0xFFu;
            if (c) {
                atomicAdd(&lhist[c], 1);
                int slot = atomicAdd(&lrun, 1);
                if (slot < CCB) {
                    uint32_t local = (uint32_t)i * 4u + (uint32_t)j;
                    uint32_t A = local >> 9, C = local & 511u, B = bkt ^ A;
                    uint32_t di = (A << 15) | (B << 9) | C;
                    cmp[slot] = ((255u - c) << DBITS) | di;
                }
            }
        }
    }
    __syncthreads();
    histb[((size_t)b * NBKT + bkt) * HBINS + t] = (uint16_t)lhist[t];  // bins <= 32768
    if (t == 0) ccnt[b * NBKT + (int)bkt] = lrun < CCB ? lrun : CCB;
}

// Per batch: fill winners, wave-parallel hist sum, suffix scan -> T, flattened-padded
// filter (independent uint4 loads, fully pipelined), rank-by-counting (LDS broadcast,
// zero barriers), winner-hash insert.
__global__ void __launch_bounds__(1024) sortrank_kernel(const uint32_t* __restrict__ compact,
                                                        const int* __restrict__ ccnt,
                                                        const uint16_t* __restrict__ histb,
                                                        unsigned int* __restrict__ winners) {
    __shared__ uint32_t s[CAP];  // 32 KB
    __shared__ int ls[HBINS];
    __shared__ int lc[NBKT];
    __shared__ int sT, sScnt;
    int b = blockIdx.x;
    int t = threadIdx.x;
    unsigned int* wb = winners + (size_t)b * WSIZE;
    for (int i = t; i < WSIZE; i += 1024) wb[i] = WEMPTY;  // in-kernel init
    if (t == 0) { sT = 1; sScnt = 0; }
    if (t < NBKT) lc[t] = ccnt[b * NBKT + t];
    if (t < HBINS) ls[t] = 0;
    __syncthreads();
    {   // hist sum: 4 threads per bin, 16 buckets each
        int bin = t & 255, grp = t >> 8;
        if (bin >= 1) {
            int sum = 0;
#pragma unroll
            for (int k = 0; k < 16; ++k)
                sum += histb[((size_t)b * NBKT + (grp * 16 + k)) * HBINS + bin];
            if (sum) atomicAdd(&ls[bin], sum);
        }
    }
    __syncthreads();
    for (int off = 1; off < HBINS; off <<= 1) {  // suffix scan; ALL threads at barriers
        int v = 0;
        if (t < HBINS && t + off < HBINS) v = ls[t + off];
        __syncthreads();
        if (t < HBINS) ls[t] += v;
        __syncthreads();
    }
    int U = ls[1];
    int mode = (U > KTOP) ? 1 : 0;
    if (mode && t >= 1 && t < HBINS && ls[t] >= KTOP && (t == HBINS - 1 || ls[t + 1] < KTOP))
        sT = t;  // unique such t
    __syncthreads();
    uint32_t T = mode ? (uint32_t)sT : 1u;
    uint32_t maxtop = 255u - T;  // keep entries with count >= T
    const uint32_t* cmpb = compact + (size_t)b * NBKT * CCB;
    for (int i = t; i < NBKT * CCB / 4; i += 1024) {  // 48 independent uint4 iterations
        int f = i * 4;
        int bk = f / CCB;
        int rem = f - bk * CCB;
        int nv = lc[bk] - rem;
        if (nv <= 0) continue;
        uint4 v4 = *(const uint4*)&cmpb[f];
        uint32_t vv[4] = {v4.x, v4.y, v4.z, v4.w};
#pragma unroll
        for (int j = 0; j < 4; ++j) {
            if (j >= nv) break;
            uint32_t e = vv[j];
            if (!mode || (e >> DBITS) <= maxtop) {
                uint32_t key = mode ? e : (e & (DSIZE - 1u));  // mode0: rank by di only
                int idx = atomicAdd(&sScnt, 1);
                if (idx < CAP) s[idx] = key;
            }
        }
    }
    __syncthreads();
    int nk = sScnt < CAP ? sScnt : CAP;
    int nsel = mode ? (nk < KTOP ? nk : KTOP) : nk;  // mode0: nk = U <= 512
    // rank-by-counting: keys unique; rank = #{smaller}. LDS broadcast reads, no barriers.
    for (int j = t; j < nk; j += 1024) {
        uint32_t key = s[j];
        int r = 0;
#pragma unroll 4
        for (int i = 0; i < nk; ++i) r += (s[i] < key) ? 1 : 0;
        if (r < nsel) {
            uint32_t di = key & (DSIZE - 1u);
            uint32_t ins = (di << 9) | (uint32_t)r;  // 30 bits, != WEMPTY
            uint32_t h = (di * 0x9E3779B1u) >> (32 - WBITS);
            while (atomicCAS(&wb[h], WEMPTY, ins) != WEMPTY) h = (h + 1) & WMASK;
        }
    }
}

// Recompute didx per point (coords L3-hot); probe 8 KB winner hash; -1 on first empty.
__global__ void label_kernel(const float* __restrict__ coords,
                             const unsigned int* __restrict__ winners,
                             int* __restrict__ out) {
    int id = blockIdx.x;
    int b = id & 15;
    int q = (id >> 4) * 256 + threadIdx.x;
    if (q >= QPTS) return;
    uint32_t di[4];
    didx4_of(coords + (size_t)b * NPTS * 3, q, di);
    const unsigned int* wb = winners + (size_t)b * WSIZE;
    int r[4];
#pragma unroll
    for (int u = 0; u < 4; ++u) {
        uint32_t h = (di[u] * 0x9E3779B1u) >> (32 - WBITS);
        int rr = -1;
        while (true) {
            unsigned int w = wb[h];
            if (w == WEMPTY) break;
            if ((w >> 9) == di[u]) { rr = (int)(w & 0x1FFu); break; }
            h = (h + 1) & WMASK;
        }
        r[u] = rr;
    }
    ivec4 r4 = {r[0], r[1], r[2], r[3]};
    __builtin_nontemporal_store(r4, (ivec4*)(out + (size_t)b * NPTS + (size_t)q * 4));
}

extern "C" void kernel_launch(void* const* d_in, const int* in_sizes, int n_in,
                              void* d_out, int out_size, void* d_ws, size_t ws_size,
                              hipStream_t stream) {
    const float* coords = (const float*)d_in[0];
    int* out = (int*)d_out;
    char* ws = (char*)d_ws;

    size_t off = 0;
    uint16_t* lists = (uint16_t*)(ws + off);   off += (size_t)BATCH * NBKT * SCB * BCAP * 2;  // 48.2 MB
    uint32_t* compact = (uint32_t*)(ws + off); off += (size_t)BATCH * NBKT * CCB * 4;         // 12.6 MB
    uint8_t* cnts = (uint8_t*)(ws + off);      off += (size_t)BATCH * NBKT * 256;             // 256 KB
    uint16_t* histb = (uint16_t*)(ws + off);   off += (size_t)BATCH * NBKT * HBINS * 2;       // 512 KB
    int* ccnt = (int*)(ws + off);              off += (size_t)BATCH * NBKT * 4;               // 4 KB
    unsigned int* winners = (unsigned int*)(ws + off); off += (size_t)BATCH * WSIZE * 4;      // 128 KB

    // NO init dispatch: every word read by a kernel is written earlier in THIS launch.
    scatter_kernel<<<SCB * BATCH, SCT, 0, stream>>>(coords, lists, cnts);
    count_kernel<<<NBKT * BATCH, 256, 0, stream>>>(lists, cnts, compact, ccnt, histb);
    sortrank_kernel<<<BATCH, 1024, 0, stream>>>(compact, ccnt, histb, winners);
    label_kernel<<<CHQ * BATCH, 256, 0, stream>>>(coords, winners, out);
}